// Round 9
// baseline (395.732 us; speedup 1.0000x reference)
//
#include <hip/hip_runtime.h>
#include <hip/hip_bf16.h>

#define BB 64
#define NJ 30
#define NM 20
#define NN 600
#define HH 128
#define NROWS (BB*NN)   // 38400
#define CAP 48          // max neighbors kept (E~7, P(>47) ~ 0)

typedef __attribute__((ext_vector_type(8))) short short8;
typedef __attribute__((ext_vector_type(4))) float f32x4;

// ---- workspace byte offsets ----
#define STATS_B   0           // slot0: 5 scalars; slots1-3: sum[128],sq[128]
#define FLAGS_B   36864
#define ZERO_B    36880       // memset range
#define WTB_B     37120       // 3 x 128x128 bf16 transposed weights (98304 B)
#define NBRCNT_B  143104
#define NBRIDX_B  296704      // NROWS*CAP ints (7372800 B)
#define POOLED0_B 7669504     // NROWS * 2 floats
#define T1_B      7976704     // NROWS*H bf16: t1, then t3 (9.83 MB)
#define P1_B      27637504    // NROWS*H bf16: t2 (9.83 MB)

// ---- output float offsets ----
#define OUT_ENT   0
#define OUT_V     64
#define OUT_LOGA  128
#define OUT_ANODE 192
#define OUT_AFEAT 1472
#define OUT_MMCH  9664
#define OUT_HPOOL 10944

__device__ __forceinline__ bool mask_at(const void* p, int layout, long i) {
    if (layout == 2) return ((const float*)p)[i] != 0.f;
    if (layout == 1) return ((const unsigned char*)p)[i] != 0;
    return ((const int*)p)[i] != 0;
}

__device__ __forceinline__ short bf16rne(float f) {
    unsigned u = __float_as_uint(f);
    return (short)((u + 0x7fffu + ((u >> 16) & 1u)) >> 16);
}
__device__ __forceinline__ float bf2f(unsigned h) {
    return __uint_as_float(h << 16);
}
__device__ __forceinline__ unsigned packbf(float a, float b) {
    return ((unsigned)(unsigned short)bf16rne(a)) |
           (((unsigned)(unsigned short)bf16rne(b)) << 16);
}

// --- scan adj once: neighbor lists + pooled0 = sum_nbr x (shfl_up scan).
//     First 289 blocks additionally do the prologue work (mask-layout detect
//     blocks 0..96, weight transpose/cvt blocks 97..288). ---
__global__ __launch_bounds__(256) void k_sparse(const float* __restrict__ adj,
                                                const float* __restrict__ x,
                                                int* __restrict__ nbr_cnt,
                                                int* __restrict__ nbr_idx,
                                                float* __restrict__ pooled0,
                                                const void* mask_p, const void* maskmch_p,
                                                int* flags,
                                                const float* __restrict__ Wa,
                                                const float* __restrict__ Wb,
                                                const float* __restrict__ Wc,
                                                unsigned short* __restrict__ wT) {
    int bid = blockIdx.x;
    int tid = threadIdx.x;
    if (bid < 289) {
        if (bid >= 97) {   // wconv: wT[c][k] = bf16(W[k][c])
            int bid2 = bid - 97;
            int mat = bid2 >> 6;
            int idx = ((bid2 & 63) << 8) + tid;
            const float* W = mat == 0 ? Wa : (mat == 1 ? Wb : Wc);
            int k = idx >> 7, c = idx & 127;
            wT[mat * 16384 + c * HH + k] = (unsigned short)bf16rne(W[idx]);
        } else {
            unsigned agg = 0;
            int which;
            if (bid == 0) {
                which = 0;
                const unsigned* p = (const unsigned*)mask_p;     // 480 words
                unsigned w0 = (tid < 480) ? p[tid] : 0u;
                unsigned w1 = (tid + 256 < 480) ? p[tid + 256] : 0u;
                agg = w0 | w1;
            } else {
                which = 1;
                const unsigned* p = (const unsigned*)maskmch_p + (size_t)(bid - 1) * 200;
                agg = (tid < 200) ? p[tid] : 0u;                 // 96 blocks x 200 words
            }
            int f = 0;
            if (((agg >> 24) & 0xffu) == 0x3fu) f |= 1;
            if ((((agg >> 8) & 0xffu) == 1u) || (((agg >> 16) & 0xffu) == 1u) ||
                (((agg >> 24) & 0xffu) == 1u)) f |= 2;
#pragma unroll
            for (int off = 1; off < 64; off <<= 1) f |= __shfl_xor(f, off);
            if ((tid & 63) == 0 && f) atomicOr(&flags[which], f);
        }
    }

    int wrow = bid * 4 + (tid >> 6);
    int lane = tid & 63;
    int b = wrow / NN;
    const float4* arow = (const float4*)(adj + (size_t)wrow * NN);
    int* irow = nbr_idx + (size_t)wrow * CAP;
    const float* xb = x + (size_t)b * NN * 2;
    float4 vv[3];
    vv[0] = arow[lane];
    vv[1] = arow[64 + lane];
    vv[2] = (128 + lane < 150) ? arow[128 + lane] : make_float4(0.f, 0.f, 0.f, 0.f);
    int cnt = 0;
    float p0 = 0.f, p1 = 0.f;
#pragma unroll
    for (int it = 0; it < 3; ++it) {
        float4 v = vv[it];
        int col0 = it * 256 + lane * 4;
        bool m0 = v.x != 0.f, m1 = v.y != 0.f, m2 = v.z != 0.f, m3 = v.w != 0.f;
        int c_lane = (int)m0 + (int)m1 + (int)m2 + (int)m3;
        int inc = c_lane;
#pragma unroll
        for (int off = 1; off < 64; off <<= 1) {
            int t = __shfl_up(inc, off);
            if (lane >= off) inc += t;
        }
        int pos = cnt + inc - c_lane;
        if (m0) {
            if (pos < CAP) irow[pos] = col0;
            float2 xv = *(const float2*)&xb[col0 * 2];
            p0 += xv.x; p1 += xv.y; ++pos;
        }
        if (m1) {
            if (pos < CAP) irow[pos] = col0 + 1;
            float2 xv = *(const float2*)&xb[(col0 + 1) * 2];
            p0 += xv.x; p1 += xv.y; ++pos;
        }
        if (m2) {
            if (pos < CAP) irow[pos] = col0 + 2;
            float2 xv = *(const float2*)&xb[(col0 + 2) * 2];
            p0 += xv.x; p1 += xv.y; ++pos;
        }
        if (m3) {
            if (pos < CAP) irow[pos] = col0 + 3;
            float2 xv = *(const float2*)&xb[(col0 + 3) * 2];
            p0 += xv.x; p1 += xv.y; ++pos;
        }
        cnt += __shfl(inc, 63);
    }
#pragma unroll
    for (int off = 1; off < 64; off <<= 1) {
        p0 += __shfl_xor(p0, off);
        p1 += __shfl_xor(p1, off);
    }
    if (lane == 0) {
        nbr_cnt[wrow] = cnt < CAP ? cnt : CAP;
        pooled0[(size_t)wrow * 2]     = p0;
        pooled0[(size_t)wrow * 2 + 1] = p1;
    }
}

// --- 5-scalar stats over pooled0 ---
__global__ __launch_bounds__(256) void k_p0stats(const float* __restrict__ pooled0,
                                                 float* __restrict__ out5) {
    __shared__ float red[4][5];
    int i = blockIdx.x * 256 + threadIdx.x;
    float p0 = pooled0[(size_t)i * 2], p1 = pooled0[(size_t)i * 2 + 1];
    float v[5] = {p0, p1, p0 * p0, p1 * p1, p0 * p1};
#pragma unroll
    for (int j = 0; j < 5; ++j)
#pragma unroll
        for (int off = 1; off < 64; off <<= 1) v[j] += __shfl_xor(v[j], off);
    int lane = threadIdx.x & 63, w = threadIdx.x >> 6;
    if (lane == 0)
#pragma unroll
        for (int j = 0; j < 5; ++j) red[w][j] = v[j];
    __syncthreads();
    if (threadIdx.x == 0)
#pragma unroll
        for (int j = 0; j < 5; ++j)
            atomicAdd(&out5[j], red[0][j] + red[1][j] + red[2][j] + red[3][j]);
}

// --- MFMA GEMM stage, column-split: 2400 blocks;
//     block bx: rows (bx>>2)*64..+63, cols (bx&3)*32..+31. ---
template<int MODE>
__global__ __launch_bounds__(256) void k_stage(const void* __restrict__ t_in_v,
                                               const float* __restrict__ pooled0,
                                               const float* __restrict__ W1,
                                               const unsigned short* __restrict__ wT,
                                               const float* __restrict__ stats_in,
                                               unsigned short* __restrict__ t_out,
                                               float* __restrict__ stats_out) {
    __shared__ float sm_mean[HH], sm_inv[HH];
    __shared__ float smS[4][32], smQ[4][32];
    int tid = threadIdx.x;
    if (MODE == 0 && tid < HH) {
        float S0 = stats_in[0], S1 = stats_in[1], Q0 = stats_in[2], Q1 = stats_in[3], P01 = stats_in[4];
        float w0 = W1[tid], w1 = W1[HH + tid];
        float m = (S0 * w0 + S1 * w1) * (1.f / NROWS);
        float eq = (Q0 * w0 * w0 + Q1 * w1 * w1 + 2.f * P01 * w0 * w1) * (1.f / NROWS);
        sm_mean[tid] = m;
        sm_inv[tid] = 1.f / sqrtf(eq - m * m + 1e-5f);
    }
    if (MODE == 1 && tid < HH) {
        float s = stats_in[tid], q = stats_in[HH + tid];
        float m = s * (1.f / NROWS);
        sm_mean[tid] = m;
        sm_inv[tid] = 1.f / sqrtf(q * (1.f / NROWS) - m * m + 1e-5f);
    }
    __syncthreads();

    const unsigned short* tin = (const unsigned short*)t_in_v;
    int lane = tid & 63, wave = tid >> 6;
    int r16 = lane & 15, kg = lane >> 4;
    int rowbase = (blockIdx.x >> 2) * 64 + wave * 16;
    int colq = blockIdx.x & 3;

    f32x4 acc[2];
#pragma unroll
    for (int t = 0; t < 2; ++t)
#pragma unroll
        for (int i = 0; i < 4; ++i) acc[t][i] = 0.f;

    float p0 = 0.f, p1 = 0.f;
    if (MODE == 0) {
        p0 = pooled0[(size_t)(rowbase + r16) * 2];
        p1 = pooled0[(size_t)(rowbase + r16) * 2 + 1];
    }

#pragma unroll
    for (int ks = 0; ks < 4; ++ks) {
        int kb = ks * 32 + kg * 8;
        short8 afr;
        {
            float av[8];
            if (MODE == 0) {
                float4 wa0 = *(const float4*)&W1[kb];
                float4 wa1 = *(const float4*)&W1[kb + 4];
                float4 wb0 = *(const float4*)&W1[HH + kb];
                float4 wb1 = *(const float4*)&W1[HH + kb + 4];
                av[0] = p0 * wa0.x + p1 * wb0.x; av[1] = p0 * wa0.y + p1 * wb0.y;
                av[2] = p0 * wa0.z + p1 * wb0.z; av[3] = p0 * wa0.w + p1 * wb0.w;
                av[4] = p0 * wa1.x + p1 * wb1.x; av[5] = p0 * wa1.y + p1 * wb1.y;
                av[6] = p0 * wa1.z + p1 * wb1.z; av[7] = p0 * wa1.w + p1 * wb1.w;
            } else {
                short8 raw = *(const short8*)&tin[(size_t)(rowbase + r16) * HH + kb];
#pragma unroll
                for (int j = 0; j < 8; ++j) av[j] = bf2f((unsigned short)raw[j]);
            }
            float4 m0 = *(const float4*)&sm_mean[kb];
            float4 m1 = *(const float4*)&sm_mean[kb + 4];
            float4 i0 = *(const float4*)&sm_inv[kb];
            float4 i1 = *(const float4*)&sm_inv[kb + 4];
            av[0] = fmaxf((av[0] - m0.x) * i0.x, 0.f);
            av[1] = fmaxf((av[1] - m0.y) * i0.y, 0.f);
            av[2] = fmaxf((av[2] - m0.z) * i0.z, 0.f);
            av[3] = fmaxf((av[3] - m0.w) * i0.w, 0.f);
            av[4] = fmaxf((av[4] - m1.x) * i1.x, 0.f);
            av[5] = fmaxf((av[5] - m1.y) * i1.y, 0.f);
            av[6] = fmaxf((av[6] - m1.z) * i1.z, 0.f);
            av[7] = fmaxf((av[7] - m1.w) * i1.w, 0.f);
#pragma unroll
            for (int j = 0; j < 8; ++j) afr[j] = bf16rne(av[j]);
        }
#pragma unroll
        for (int t = 0; t < 2; ++t) {
            short8 bfr = *(const short8*)&wT[(size_t)((colq * 2 + t) * 16 + r16) * HH + kb];
            acc[t] = __builtin_amdgcn_mfma_f32_16x16x32_bf16(afr, bfr, acc[t], 0, 0, 0);
        }
    }

#pragma unroll
    for (int t = 0; t < 2; ++t) {
        int lc = t * 16 + r16;
        int col = colq * 32 + lc;
        float s = 0.f, q = 0.f;
#pragma unroll
        for (int i = 0; i < 4; ++i) {
            float v = acc[t][i];
            t_out[(size_t)(rowbase + kg * 4 + i) * HH + col] = (unsigned short)bf16rne(v);
            s += v; q += v * v;
        }
        s += __shfl_xor(s, 16); q += __shfl_xor(q, 16);
        s += __shfl_xor(s, 32); q += __shfl_xor(q, 32);
        if (kg == 0) { smS[wave][lc] = s; smQ[wave][lc] = q; }
    }
    __syncthreads();
    if (tid < 32) {
        int col = colq * 32 + tid;
        atomicAdd(&stats_out[col],      smS[0][tid] + smS[1][tid] + smS[2][tid] + smS[3][tid]);
        atomicAdd(&stats_out[HH + col], smQ[0][tid] + smQ[1][tid] + smQ[2][tid] + smQ[3][tid]);
    }
}

// --- FUSED pool1 + stage2: block = 32 rows x 128 cols.
//     Phase A: gather pooled1 (bf16-rounded, same rounding point as unfused ->
//     bit-identical t2) into LDS. Phase B: MFMA from LDS.
//     NOTE: t_out MUST be a different buffer than t1 — the gather reads
//     arbitrary neighbor rows of t1 across blocks (in-place = race, R8 bug). ---
__global__ __launch_bounds__(256) void k_poolstage(const unsigned short* __restrict__ t1,
                                                   const int* __restrict__ nbr_cnt,
                                                   const int* __restrict__ nbr_idx,
                                                   const float* __restrict__ stats1,
                                                   const unsigned short* __restrict__ wT,
                                                   unsigned short* __restrict__ t_out,
                                                   float* __restrict__ stats_out) {
    __shared__ float sm_mean[HH], sm_inv[HH];
    __shared__ unsigned short shA[32 * HH];   // 8 KB
    __shared__ float smS[4][HH], smQ[4][HH];
    int tid = threadIdx.x;
    if (tid < HH) {
        float s = stats1[tid], q = stats1[HH + tid];
        float m = s * (1.f / NROWS);
        sm_mean[tid] = m;
        sm_inv[tid] = 1.f / sqrtf(q * (1.f / NROWS) - m * m + 1e-5f);
    }
    __syncthreads();
    int rowbase = blockIdx.x * 32;

    {   // gather: thread (r = tid>>3, cg = tid&7) covers cols cg*16..+15
        int r = tid >> 3, cg = tid & 7;
        int row = rowbase + r;
        int b = row / NN;
        int cnt = nbr_cnt[row];
        const int* ir = nbr_idx + (size_t)row * CAP;
        const unsigned short* tb = t1 + (size_t)b * NN * HH + cg * 16;
        float accv[16];
#pragma unroll
        for (int j = 0; j < 16; ++j) accv[j] = 0.f;
        float mloc[16], iloc[16];
#pragma unroll
        for (int j = 0; j < 16; ++j) {
            mloc[j] = sm_mean[cg * 16 + j];
            iloc[j] = sm_inv[cg * 16 + j];
        }
        for (int i = 0; i < cnt; ++i) {
            int m_ = ir[i];
            const unsigned short* p = tb + (size_t)m_ * HH;
            uint2 w0 = *(const uint2*)(p);
            uint2 w1 = *(const uint2*)(p + 4);
            uint2 w2 = *(const uint2*)(p + 8);
            uint2 w3 = *(const uint2*)(p + 12);
            unsigned wsv[8] = {w0.x, w0.y, w1.x, w1.y, w2.x, w2.y, w3.x, w3.y};
#pragma unroll
            for (int j = 0; j < 8; ++j) {
                accv[2 * j]     += fmaxf((bf2f(wsv[j] & 0xffffu) - mloc[2 * j])     * iloc[2 * j], 0.f);
                accv[2 * j + 1] += fmaxf((bf2f(wsv[j] >> 16)     - mloc[2 * j + 1]) * iloc[2 * j + 1], 0.f);
            }
        }
        unsigned short* dst = &shA[r * HH + cg * 16];
#pragma unroll
        for (int j = 0; j < 8; ++j)
            *(unsigned*)(dst + 2 * j) = packbf(accv[2 * j], accv[2 * j + 1]);
    }
    __syncthreads();

    // MFMA: wave w -> rows 16*(w&1).., coltiles 4*(w>>1)..+3
    int lane = tid & 63, w = tid >> 6;
    int r16 = lane & 15, kg = lane >> 4;
    int rhalf = w & 1, chalf = w >> 1;
    int rloc = rhalf * 16 + r16;
    short8 afr[4];
#pragma unroll
    for (int ks = 0; ks < 4; ++ks)
        afr[ks] = *(const short8*)&shA[rloc * HH + ks * 32 + kg * 8];
    f32x4 acc[4];
#pragma unroll
    for (int t = 0; t < 4; ++t)
#pragma unroll
        for (int i = 0; i < 4; ++i) acc[t][i] = 0.f;
#pragma unroll
    for (int t = 0; t < 4; ++t) {
        int coltile = chalf * 4 + t;
#pragma unroll
        for (int ks = 0; ks < 4; ++ks) {
            short8 bfr = *(const short8*)&wT[(size_t)(coltile * 16 + r16) * HH + ks * 32 + kg * 8];
            acc[t] = __builtin_amdgcn_mfma_f32_16x16x32_bf16(afr[ks], bfr, acc[t], 0, 0, 0);
        }
    }
#pragma unroll
    for (int t = 0; t < 4; ++t) {
        int col = (chalf * 4 + t) * 16 + r16;
        float s = 0.f, q = 0.f;
#pragma unroll
        for (int i = 0; i < 4; ++i) {
            float v = acc[t][i];
            t_out[(size_t)(rowbase + rhalf * 16 + kg * 4 + i) * HH + col] = (unsigned short)bf16rne(v);
            s += v; q += v * v;
        }
        s += __shfl_xor(s, 16); q += __shfl_xor(q, 16);
        s += __shfl_xor(s, 32); q += __shfl_xor(q, 32);
        if (kg == 0) { smS[w][col] = s; smQ[w][col] = q; }
    }
    __syncthreads();
    if (tid < HH) {
        int col = tid;
        float s, q;
        if (col < 64) { s = smS[0][col] + smS[1][col]; q = smQ[0][col] + smQ[1][col]; }
        else          { s = smS[2][col] + smS[3][col]; q = smQ[2][col] + smQ[3][col]; }
        atomicAdd(&stats_out[col], s);
        atomicAdd(&stats_out[HH + col], q);
    }
}

// --- FUSED tail: per-b block computes hpool (in LDS), actor MLP (with
//     row-invariant 2/3 of the concat GEMM hoisted), critic, softmax, gathers. ---
__global__ __launch_bounds__(256) void k_tail(const unsigned short* __restrict__ t3,
                                              const float* __restrict__ gp,
                                              const float* __restrict__ stats3,
                                              const int* __restrict__ cand,
                                              const float* __restrict__ mch,
                                              const void* __restrict__ mask_p,
                                              const void* __restrict__ maskmch_p,
                                              const int* __restrict__ flags,
                                              const float* __restrict__ dur,
                                              const int* __restrict__ a_index,
                                              const int* __restrict__ old_action,
                                              const float* __restrict__ Wa1,
                                              const float* __restrict__ ba1,
                                              const float* __restrict__ Wa2,
                                              const float* __restrict__ ba2,
                                              const float* __restrict__ Wa3,
                                              const float* __restrict__ ba3,
                                              const float* __restrict__ Wc1,
                                              const float* __restrict__ bc1,
                                              const float* __restrict__ Wc2,
                                              const float* __restrict__ bc2,
                                              float* __restrict__ out) {
    __shared__ float sm_mean[HH], sm_inv[HH], sh_hp[HH], sh_mch[HH], sh_red[HH];
    __shared__ float red8[8][HH];
    __shared__ float sh_cand[NJ][HH];
    __shared__ float sh_a1[NJ][HH];
    __shared__ float sh_sc[NJ][132];
    __shared__ float sh_s[32], sh_lp[32];
    __shared__ int sh_m[32];
    int b = blockIdx.x, tid = threadIdx.x;

    if (tid < HH) {
        float s = stats3[tid], q = stats3[HH + tid];
        float m = s * (1.f / NROWS);
        sm_mean[tid] = m;
        sm_inv[tid] = 1.f / sqrtf(q * (1.f / NROWS) - m * m + 1e-5f);
        sh_mch[tid] = mch[b * HH + tid];
    }
    __syncthreads();

    // hpool = sum_n gp * relu(BN3(t3))
    {
        int c4 = tid & 31, rl = tid >> 5;
        float4 mm = *(const float4*)&sm_mean[c4 * 4];
        float4 iv = *(const float4*)&sm_inv[c4 * 4];
        float a0 = 0.f, a1 = 0.f, a2 = 0.f, a3 = 0.f;
        for (int n = rl; n < NN; n += 8) {
            float w = gp[b * NN + n];
            uint2 t = *(const uint2*)&t3[((size_t)b * NN + n) * HH + c4 * 4];
            a0 += w * fmaxf((bf2f(t.x & 0xffffu) - mm.x) * iv.x, 0.f);
            a1 += w * fmaxf((bf2f(t.x >> 16)     - mm.y) * iv.y, 0.f);
            a2 += w * fmaxf((bf2f(t.y & 0xffffu) - mm.z) * iv.z, 0.f);
            a3 += w * fmaxf((bf2f(t.y >> 16)     - mm.w) * iv.w, 0.f);
        }
        *(float4*)&red8[rl][c4 * 4] = make_float4(a0, a1, a2, a3);
    }
    __syncthreads();
    if (tid < HH) {
        float s = 0.f;
#pragma unroll
        for (int g = 0; g < 8; ++g) s += red8[g][tid];
        sh_hp[tid] = s;
    }
    __syncthreads();

    int c = tid & 127, slot = tid >> 7;
    float mean_c = sm_mean[c], inv_c = sm_inv[c];

    // candidate features + row-invariant part of a1
    for (int r = slot; r < NJ; r += 2) {
        int cd = cand[b * NJ + r];
        float v = bf2f(t3[((size_t)b * NN + cd) * HH + c]);
        sh_cand[r][c] = fmaxf((v - mean_c) * inv_c, 0.f);
    }
    {
        float part = 0.f;
        const float* src = (slot == 0) ? sh_hp : sh_mch;
        const float* Wp  = Wa1 + (size_t)(slot == 0 ? 128 : 256) * HH;
        for (int k = 0; k < HH; ++k) part += src[k] * Wp[(size_t)k * HH + c];
        red8[slot][c] = part;
    }
    __syncthreads();
    float b2 = red8[0][c] + red8[1][c] + ba1[c];

    // a1 = tanh(cand-part + b2)
    for (int r = slot; r < NJ; r += 2) {
        float acc = b2;
        for (int k = 0; k < HH; ++k) acc += sh_cand[r][k] * Wa1[(size_t)k * HH + c];
        sh_a1[r][c] = tanhf(acc);
    }
    __syncthreads();

    // a2 + Wa3 dot
    {
        float w3 = Wa3[c], bb2 = ba2[c];
        for (int r = slot; r < NJ; r += 2) {
            float acc2 = bb2;
            for (int k = 0; k < HH; ++k) acc2 += sh_a1[r][k] * Wa2[(size_t)k * HH + c];
            sh_sc[r][c] = tanhf(acc2) * w3;
        }
    }
    __syncthreads();
    if (tid < NJ) {
        float s = 0.f;
        for (int c2 = 0; c2 < HH; ++c2) s += sh_sc[tid][c2];
        sh_s[tid] = 10.f * (s + ba3[0]);
    }

    // critic
    if (tid < HH) {
        float a = bc1[tid];
        for (int k = 0; k < HH; ++k) a += sh_hp[k] * Wc1[(size_t)k * HH + tid];
        sh_red[tid] = tanhf(a) * Wc2[tid];
    }
    __syncthreads();
    for (int st = 64; st > 0; st >>= 1) {
        if (tid < st) sh_red[tid] += sh_red[tid + st];
        __syncthreads();
    }
    if (tid == 0) out[OUT_V + b] = sh_red[0] + bc2[0];

    // softmax / entropy / log_a
    int fA = flags[0], fB = flags[1];
    int layA = (fA & 1) ? 2 : ((fA & 2) ? 1 : 0);
    int layB = (fB & 1) ? 2 : ((fB & 2) ? 1 : 0);
    if (tid < NJ) sh_m[tid] = mask_at(mask_p, layA, (long)b * NJ + tid) ? 1 : 0;
    __syncthreads();
    if (tid == 0) {
        float mx = -1e30f;
        for (int j = 0; j < NJ; ++j)
            if (!sh_m[j] && sh_s[j] > mx) mx = sh_s[j];
        float sum = 0.f;
        for (int j = 0; j < NJ; ++j)
            if (!sh_m[j]) sum += expf(sh_s[j] - mx);
        float lse = mx + logf(sum);
        float ent = 0.f;
        for (int j = 0; j < NJ; ++j) {
            if (!sh_m[j]) {
                float lp = sh_s[j] - lse;
                sh_lp[j] = lp;
                float pi = expf(lp);
                if (pi > 0.f) ent -= pi * lp;
            }
        }
        out[OUT_ENT + b] = ent;
        out[OUT_LOGA + b] = sh_lp[a_index[b]];
    }

    // gathers
    int old = old_action[b];
    if (tid < NM) {
        out[OUT_ANODE + b * NM + tid] = dur[((size_t)b * NN + old) * NM + tid];
        out[OUT_MMCH + b * NM + tid] =
            mask_at(maskmch_p, layB, ((size_t)b * NN + old) * NM + tid) ? 1.f : 0.f;
    }
    if (tid < HH) {
        float v = bf2f(t3[((size_t)b * NN + old) * HH + tid]);
        out[OUT_AFEAT + b * HH + tid] = fmaxf((v - mean_c) * inv_c, 0.f);
        out[OUT_HPOOL + b * HH + tid] = sh_hp[tid];
    }
}

extern "C" void kernel_launch(void* const* d_in, const int* in_sizes, int n_in,
                              void* d_out, int out_size, void* d_ws, size_t ws_size,
                              hipStream_t stream) {
    (void)in_sizes; (void)n_in; (void)out_size; (void)ws_size;
    const float* x         = (const float*)d_in[0];
    const float* gp        = (const float*)d_in[1];
    const float* adj       = (const float*)d_in[3];
    const int*   cand      = (const int*)d_in[4];
    const void*  mask_p    = d_in[5];
    const void*  maskmch_p = d_in[6];
    const float* dur       = (const float*)d_in[7];
    const int*   a_index   = (const int*)d_in[8];
    const int*   old_act   = (const int*)d_in[9];
    const float* mch_pool  = (const float*)d_in[10];
    const float* W1_0 = (const float*)d_in[11];
    const float* W2_0 = (const float*)d_in[13];
    const float* W1_1 = (const float*)d_in[15];
    const float* W2_1 = (const float*)d_in[17];
    const float* Wa1  = (const float*)d_in[19];
    const float* ba1  = (const float*)d_in[20];
    const float* Wa2  = (const float*)d_in[21];
    const float* ba2  = (const float*)d_in[22];
    const float* Wa3  = (const float*)d_in[23];
    const float* ba3  = (const float*)d_in[24];
    const float* Wc1  = (const float*)d_in[25];
    const float* bc1  = (const float*)d_in[26];
    const float* Wc2  = (const float*)d_in[27];
    const float* bc2  = (const float*)d_in[28];

    char* ws = (char*)d_ws;
    float* stats   = (float*)(ws + STATS_B);
    int*   flags   = (int*)(ws + FLAGS_B);
    unsigned short* wtb = (unsigned short*)(ws + WTB_B);
    int*   nbr_cnt = (int*)(ws + NBRCNT_B);
    int*   nbr_idx = (int*)(ws + NBRIDX_B);
    float* pooled0 = (float*)(ws + POOLED0_B);
    unsigned short* t1_16 = (unsigned short*)(ws + T1_B);  // t1, then t3 (bf16)
    unsigned short* t2_16 = (unsigned short*)(ws + P1_B);  // t2 (bf16)
    float* out     = (float*)d_out;

    hipMemsetAsync(ws, 0, ZERO_B, stream);
    k_sparse<<<NROWS / 4, 256, 0, stream>>>(adj, x, nbr_cnt, nbr_idx, pooled0,
                                            mask_p, maskmch_p, flags, W2_0, W1_1, W2_1, wtb);
    k_p0stats<<<NROWS / 256, 256, 0, stream>>>(pooled0, stats);
    // t1(bf16) = relu(BN0(pooled0 @ W1_0)) @ W2_0   [+ stats1]
    k_stage<0><<<2400, 256, 0, stream>>>(nullptr, pooled0, W1_0, wtb, stats, t1_16, stats + 256);
    // t2(bf16) = (sum_nbr relu(BN1(t1))) @ W1_1   [+ stats2]  — OUT != t1 (no in-place!)
    k_poolstage<<<NROWS / 32, 256, 0, stream>>>(t1_16, nbr_cnt, nbr_idx, stats + 256,
                                                wtb + 16384, t2_16, stats + 512);
    // t3(bf16) = relu(BN2(t2)) @ W2_1   [+ stats3]  — in t2_16, out t1_16
    k_stage<1><<<2400, 256, 0, stream>>>(t2_16, nullptr, nullptr, wtb + 32768, stats + 512,
                                         t1_16, stats + 768);
    k_tail<<<BB, 256, 0, stream>>>(t1_16, gp, stats + 768, cand, mch_pool,
                                   mask_p, maskmch_p, flags, dur, a_index, old_act,
                                   Wa1, ba1, Wa2, ba2, Wa3, ba3, Wc1, bc1, Wc2, bc2, out);
}

// Round 10
// 359.957 us; speedup vs baseline: 1.0994x; 1.0994x over previous
//
#include <hip/hip_runtime.h>
#include <hip/hip_bf16.h>

#define BB 64
#define NJ 30
#define NM 20
#define NN 600
#define HH 128
#define NROWS (BB*NN)   // 38400
#define CAP 48          // max neighbors kept (E~7, P(>47) ~ 0)

typedef __attribute__((ext_vector_type(8))) short short8;
typedef __attribute__((ext_vector_type(4))) float f32x4;

// ---- workspace byte offsets ----
#define STATS_B   0           // slot0: 5 scalars; slots1-3: sum[128],sq[128]
#define HPOOL_B   4096
#define FLAGS_B   36864
#define ZERO_B    36880       // memset range
#define WTB_B     37120       // 3 x 128x128 bf16 transposed weights (98304 B)
#define SCORES_B  135424
#define NBRCNT_B  143104
#define NBRIDX_B  296704      // NROWS*CAP ints (7372800 B)
#define POOLED0_B 7669504     // NROWS * 2 floats
#define T1_B      7976704     // NROWS*H bf16: t1, then t3 (9.83 MB)
#define P1_B      27637504    // NROWS*H bf16: t2 (9.83 MB)

// ---- output float offsets ----
#define OUT_ENT   0
#define OUT_V     64
#define OUT_LOGA  128
#define OUT_ANODE 192
#define OUT_AFEAT 1472
#define OUT_MMCH  9664
#define OUT_HPOOL 10944

__device__ __forceinline__ bool mask_at(const void* p, int layout, long i) {
    if (layout == 2) return ((const float*)p)[i] != 0.f;
    if (layout == 1) return ((const unsigned char*)p)[i] != 0;
    return ((const int*)p)[i] != 0;
}

__device__ __forceinline__ short bf16rne(float f) {
    unsigned u = __float_as_uint(f);
    return (short)((u + 0x7fffu + ((u >> 16) & 1u)) >> 16);
}
__device__ __forceinline__ float bf2f(unsigned h) {
    return __uint_as_float(h << 16);
}
__device__ __forceinline__ unsigned packbf(float a, float b) {
    return ((unsigned)(unsigned short)bf16rne(a)) |
           (((unsigned)(unsigned short)bf16rne(b)) << 16);
}

// --- scan adj once: neighbor lists + pooled0 = sum_nbr x (shfl_up scan).
//     First 289 blocks additionally do the prologue work (mask-layout detect
//     blocks 0..96, weight transpose/cvt blocks 97..288). ---
__global__ __launch_bounds__(256) void k_sparse(const float* __restrict__ adj,
                                                const float* __restrict__ x,
                                                int* __restrict__ nbr_cnt,
                                                int* __restrict__ nbr_idx,
                                                float* __restrict__ pooled0,
                                                const void* mask_p, const void* maskmch_p,
                                                int* flags,
                                                const float* __restrict__ Wa,
                                                const float* __restrict__ Wb,
                                                const float* __restrict__ Wc,
                                                unsigned short* __restrict__ wT) {
    int bid = blockIdx.x;
    int tid = threadIdx.x;
    if (bid < 289) {
        if (bid >= 97) {   // wconv: wT[c][k] = bf16(W[k][c])
            int bid2 = bid - 97;
            int mat = bid2 >> 6;
            int idx = ((bid2 & 63) << 8) + tid;
            const float* W = mat == 0 ? Wa : (mat == 1 ? Wb : Wc);
            int k = idx >> 7, c = idx & 127;
            wT[mat * 16384 + c * HH + k] = (unsigned short)bf16rne(W[idx]);
        } else {
            unsigned agg = 0;
            int which;
            if (bid == 0) {
                which = 0;
                const unsigned* p = (const unsigned*)mask_p;     // 480 words
                unsigned w0 = (tid < 480) ? p[tid] : 0u;
                unsigned w1 = (tid + 256 < 480) ? p[tid + 256] : 0u;
                agg = w0 | w1;
            } else {
                which = 1;
                const unsigned* p = (const unsigned*)maskmch_p + (size_t)(bid - 1) * 200;
                agg = (tid < 200) ? p[tid] : 0u;                 // 96 blocks x 200 words
            }
            int f = 0;
            if (((agg >> 24) & 0xffu) == 0x3fu) f |= 1;
            if ((((agg >> 8) & 0xffu) == 1u) || (((agg >> 16) & 0xffu) == 1u) ||
                (((agg >> 24) & 0xffu) == 1u)) f |= 2;
#pragma unroll
            for (int off = 1; off < 64; off <<= 1) f |= __shfl_xor(f, off);
            if ((tid & 63) == 0 && f) atomicOr(&flags[which], f);
        }
    }

    int wrow = bid * 4 + (tid >> 6);
    int lane = tid & 63;
    int b = wrow / NN;
    const float4* arow = (const float4*)(adj + (size_t)wrow * NN);
    int* irow = nbr_idx + (size_t)wrow * CAP;
    const float* xb = x + (size_t)b * NN * 2;
    float4 vv[3];
    vv[0] = arow[lane];
    vv[1] = arow[64 + lane];
    vv[2] = (128 + lane < 150) ? arow[128 + lane] : make_float4(0.f, 0.f, 0.f, 0.f);
    int cnt = 0;
    float p0 = 0.f, p1 = 0.f;
#pragma unroll
    for (int it = 0; it < 3; ++it) {
        float4 v = vv[it];
        int col0 = it * 256 + lane * 4;
        bool m0 = v.x != 0.f, m1 = v.y != 0.f, m2 = v.z != 0.f, m3 = v.w != 0.f;
        int c_lane = (int)m0 + (int)m1 + (int)m2 + (int)m3;
        int inc = c_lane;
#pragma unroll
        for (int off = 1; off < 64; off <<= 1) {
            int t = __shfl_up(inc, off);
            if (lane >= off) inc += t;
        }
        int pos = cnt + inc - c_lane;
        if (m0) {
            if (pos < CAP) irow[pos] = col0;
            float2 xv = *(const float2*)&xb[col0 * 2];
            p0 += xv.x; p1 += xv.y; ++pos;
        }
        if (m1) {
            if (pos < CAP) irow[pos] = col0 + 1;
            float2 xv = *(const float2*)&xb[(col0 + 1) * 2];
            p0 += xv.x; p1 += xv.y; ++pos;
        }
        if (m2) {
            if (pos < CAP) irow[pos] = col0 + 2;
            float2 xv = *(const float2*)&xb[(col0 + 2) * 2];
            p0 += xv.x; p1 += xv.y; ++pos;
        }
        if (m3) {
            if (pos < CAP) irow[pos] = col0 + 3;
            float2 xv = *(const float2*)&xb[(col0 + 3) * 2];
            p0 += xv.x; p1 += xv.y; ++pos;
        }
        cnt += __shfl(inc, 63);
    }
#pragma unroll
    for (int off = 1; off < 64; off <<= 1) {
        p0 += __shfl_xor(p0, off);
        p1 += __shfl_xor(p1, off);
    }
    if (lane == 0) {
        nbr_cnt[wrow] = cnt < CAP ? cnt : CAP;
        pooled0[(size_t)wrow * 2]     = p0;
        pooled0[(size_t)wrow * 2 + 1] = p1;
    }
}

// --- 5-scalar stats over pooled0 ---
__global__ __launch_bounds__(256) void k_p0stats(const float* __restrict__ pooled0,
                                                 float* __restrict__ out5) {
    __shared__ float red[4][5];
    int i = blockIdx.x * 256 + threadIdx.x;
    float p0 = pooled0[(size_t)i * 2], p1 = pooled0[(size_t)i * 2 + 1];
    float v[5] = {p0, p1, p0 * p0, p1 * p1, p0 * p1};
#pragma unroll
    for (int j = 0; j < 5; ++j)
#pragma unroll
        for (int off = 1; off < 64; off <<= 1) v[j] += __shfl_xor(v[j], off);
    int lane = threadIdx.x & 63, w = threadIdx.x >> 6;
    if (lane == 0)
#pragma unroll
        for (int j = 0; j < 5; ++j) red[w][j] = v[j];
    __syncthreads();
    if (threadIdx.x == 0)
#pragma unroll
        for (int j = 0; j < 5; ++j)
            atomicAdd(&out5[j], red[0][j] + red[1][j] + red[2][j] + red[3][j]);
}

// --- MFMA GEMM stage, column-split: 2400 blocks;
//     block bx: rows (bx>>2)*64..+63, cols (bx&3)*32..+31. ---
template<int MODE>
__global__ __launch_bounds__(256) void k_stage(const void* __restrict__ t_in_v,
                                               const float* __restrict__ pooled0,
                                               const float* __restrict__ W1,
                                               const unsigned short* __restrict__ wT,
                                               const float* __restrict__ stats_in,
                                               unsigned short* __restrict__ t_out,
                                               float* __restrict__ stats_out) {
    __shared__ float sm_mean[HH], sm_inv[HH];
    __shared__ float smS[4][32], smQ[4][32];
    int tid = threadIdx.x;
    if (MODE == 0 && tid < HH) {
        float S0 = stats_in[0], S1 = stats_in[1], Q0 = stats_in[2], Q1 = stats_in[3], P01 = stats_in[4];
        float w0 = W1[tid], w1 = W1[HH + tid];
        float m = (S0 * w0 + S1 * w1) * (1.f / NROWS);
        float eq = (Q0 * w0 * w0 + Q1 * w1 * w1 + 2.f * P01 * w0 * w1) * (1.f / NROWS);
        sm_mean[tid] = m;
        sm_inv[tid] = 1.f / sqrtf(eq - m * m + 1e-5f);
    }
    if (MODE == 1 && tid < HH) {
        float s = stats_in[tid], q = stats_in[HH + tid];
        float m = s * (1.f / NROWS);
        sm_mean[tid] = m;
        sm_inv[tid] = 1.f / sqrtf(q * (1.f / NROWS) - m * m + 1e-5f);
    }
    __syncthreads();

    const unsigned short* tin = (const unsigned short*)t_in_v;
    int lane = tid & 63, wave = tid >> 6;
    int r16 = lane & 15, kg = lane >> 4;
    int rowbase = (blockIdx.x >> 2) * 64 + wave * 16;
    int colq = blockIdx.x & 3;

    f32x4 acc[2];
#pragma unroll
    for (int t = 0; t < 2; ++t)
#pragma unroll
        for (int i = 0; i < 4; ++i) acc[t][i] = 0.f;

    float p0 = 0.f, p1 = 0.f;
    if (MODE == 0) {
        p0 = pooled0[(size_t)(rowbase + r16) * 2];
        p1 = pooled0[(size_t)(rowbase + r16) * 2 + 1];
    }

#pragma unroll
    for (int ks = 0; ks < 4; ++ks) {
        int kb = ks * 32 + kg * 8;
        short8 afr;
        {
            float av[8];
            if (MODE == 0) {
                float4 wa0 = *(const float4*)&W1[kb];
                float4 wa1 = *(const float4*)&W1[kb + 4];
                float4 wb0 = *(const float4*)&W1[HH + kb];
                float4 wb1 = *(const float4*)&W1[HH + kb + 4];
                av[0] = p0 * wa0.x + p1 * wb0.x; av[1] = p0 * wa0.y + p1 * wb0.y;
                av[2] = p0 * wa0.z + p1 * wb0.z; av[3] = p0 * wa0.w + p1 * wb0.w;
                av[4] = p0 * wa1.x + p1 * wb1.x; av[5] = p0 * wa1.y + p1 * wb1.y;
                av[6] = p0 * wa1.z + p1 * wb1.z; av[7] = p0 * wa1.w + p1 * wb1.w;
            } else {
                short8 raw = *(const short8*)&tin[(size_t)(rowbase + r16) * HH + kb];
#pragma unroll
                for (int j = 0; j < 8; ++j) av[j] = bf2f((unsigned short)raw[j]);
            }
            float4 m0 = *(const float4*)&sm_mean[kb];
            float4 m1 = *(const float4*)&sm_mean[kb + 4];
            float4 i0 = *(const float4*)&sm_inv[kb];
            float4 i1 = *(const float4*)&sm_inv[kb + 4];
            av[0] = fmaxf((av[0] - m0.x) * i0.x, 0.f);
            av[1] = fmaxf((av[1] - m0.y) * i0.y, 0.f);
            av[2] = fmaxf((av[2] - m0.z) * i0.z, 0.f);
            av[3] = fmaxf((av[3] - m0.w) * i0.w, 0.f);
            av[4] = fmaxf((av[4] - m1.x) * i1.x, 0.f);
            av[5] = fmaxf((av[5] - m1.y) * i1.y, 0.f);
            av[6] = fmaxf((av[6] - m1.z) * i1.z, 0.f);
            av[7] = fmaxf((av[7] - m1.w) * i1.w, 0.f);
#pragma unroll
            for (int j = 0; j < 8; ++j) afr[j] = bf16rne(av[j]);
        }
#pragma unroll
        for (int t = 0; t < 2; ++t) {
            short8 bfr = *(const short8*)&wT[(size_t)((colq * 2 + t) * 16 + r16) * HH + kb];
            acc[t] = __builtin_amdgcn_mfma_f32_16x16x32_bf16(afr, bfr, acc[t], 0, 0, 0);
        }
    }

#pragma unroll
    for (int t = 0; t < 2; ++t) {
        int lc = t * 16 + r16;
        int col = colq * 32 + lc;
        float s = 0.f, q = 0.f;
#pragma unroll
        for (int i = 0; i < 4; ++i) {
            float v = acc[t][i];
            t_out[(size_t)(rowbase + kg * 4 + i) * HH + col] = (unsigned short)bf16rne(v);
            s += v; q += v * v;
        }
        s += __shfl_xor(s, 16); q += __shfl_xor(q, 16);
        s += __shfl_xor(s, 32); q += __shfl_xor(q, 32);
        if (kg == 0) { smS[wave][lc] = s; smQ[wave][lc] = q; }
    }
    __syncthreads();
    if (tid < 32) {
        int col = colq * 32 + tid;
        atomicAdd(&stats_out[col],      smS[0][tid] + smS[1][tid] + smS[2][tid] + smS[3][tid]);
        atomicAdd(&stats_out[HH + col], smQ[0][tid] + smQ[1][tid] + smQ[2][tid] + smQ[3][tid]);
    }
}

// --- FUSED pool1 + stage2 (ping-pong: reads t1, writes t2 to a DIFFERENT buffer) ---
__global__ __launch_bounds__(256) void k_poolstage(const unsigned short* __restrict__ t1,
                                                   const int* __restrict__ nbr_cnt,
                                                   const int* __restrict__ nbr_idx,
                                                   const float* __restrict__ stats1,
                                                   const unsigned short* __restrict__ wT,
                                                   unsigned short* __restrict__ t_out,
                                                   float* __restrict__ stats_out) {
    __shared__ float sm_mean[HH], sm_inv[HH];
    __shared__ unsigned short shA[32 * HH];   // 8 KB
    __shared__ float smS[4][HH], smQ[4][HH];
    int tid = threadIdx.x;
    if (tid < HH) {
        float s = stats1[tid], q = stats1[HH + tid];
        float m = s * (1.f / NROWS);
        sm_mean[tid] = m;
        sm_inv[tid] = 1.f / sqrtf(q * (1.f / NROWS) - m * m + 1e-5f);
    }
    __syncthreads();
    int rowbase = blockIdx.x * 32;

    {   // gather: thread (r = tid>>3, cg = tid&7) covers cols cg*16..+15
        int r = tid >> 3, cg = tid & 7;
        int row = rowbase + r;
        int b = row / NN;
        int cnt = nbr_cnt[row];
        const int* ir = nbr_idx + (size_t)row * CAP;
        const unsigned short* tb = t1 + (size_t)b * NN * HH + cg * 16;
        float accv[16];
#pragma unroll
        for (int j = 0; j < 16; ++j) accv[j] = 0.f;
        float mloc[16], iloc[16];
#pragma unroll
        for (int j = 0; j < 16; ++j) {
            mloc[j] = sm_mean[cg * 16 + j];
            iloc[j] = sm_inv[cg * 16 + j];
        }
        for (int i = 0; i < cnt; ++i) {
            int m_ = ir[i];
            const unsigned short* p = tb + (size_t)m_ * HH;
            uint2 w0 = *(const uint2*)(p);
            uint2 w1 = *(const uint2*)(p + 4);
            uint2 w2 = *(const uint2*)(p + 8);
            uint2 w3 = *(const uint2*)(p + 12);
            unsigned wsv[8] = {w0.x, w0.y, w1.x, w1.y, w2.x, w2.y, w3.x, w3.y};
#pragma unroll
            for (int j = 0; j < 8; ++j) {
                accv[2 * j]     += fmaxf((bf2f(wsv[j] & 0xffffu) - mloc[2 * j])     * iloc[2 * j], 0.f);
                accv[2 * j + 1] += fmaxf((bf2f(wsv[j] >> 16)     - mloc[2 * j + 1]) * iloc[2 * j + 1], 0.f);
            }
        }
        unsigned short* dst = &shA[r * HH + cg * 16];
#pragma unroll
        for (int j = 0; j < 8; ++j)
            *(unsigned*)(dst + 2 * j) = packbf(accv[2 * j], accv[2 * j + 1]);
    }
    __syncthreads();

    int lane = tid & 63, w = tid >> 6;
    int r16 = lane & 15, kg = lane >> 4;
    int rhalf = w & 1, chalf = w >> 1;
    int rloc = rhalf * 16 + r16;
    short8 afr[4];
#pragma unroll
    for (int ks = 0; ks < 4; ++ks)
        afr[ks] = *(const short8*)&shA[rloc * HH + ks * 32 + kg * 8];
    f32x4 acc[4];
#pragma unroll
    for (int t = 0; t < 4; ++t)
#pragma unroll
        for (int i = 0; i < 4; ++i) acc[t][i] = 0.f;
#pragma unroll
    for (int t = 0; t < 4; ++t) {
        int coltile = chalf * 4 + t;
#pragma unroll
        for (int ks = 0; ks < 4; ++ks) {
            short8 bfr = *(const short8*)&wT[(size_t)(coltile * 16 + r16) * HH + ks * 32 + kg * 8];
            acc[t] = __builtin_amdgcn_mfma_f32_16x16x32_bf16(afr[ks], bfr, acc[t], 0, 0, 0);
        }
    }
#pragma unroll
    for (int t = 0; t < 4; ++t) {
        int col = (chalf * 4 + t) * 16 + r16;
        float s = 0.f, q = 0.f;
#pragma unroll
        for (int i = 0; i < 4; ++i) {
            float v = acc[t][i];
            t_out[(size_t)(rowbase + rhalf * 16 + kg * 4 + i) * HH + col] = (unsigned short)bf16rne(v);
            s += v; q += v * v;
        }
        s += __shfl_xor(s, 16); q += __shfl_xor(q, 16);
        s += __shfl_xor(s, 32); q += __shfl_xor(q, 32);
        if (kg == 0) { smS[w][col] = s; smQ[w][col] = q; }
    }
    __syncthreads();
    if (tid < HH) {
        int col = tid;
        float s, q;
        if (col < 64) { s = smS[0][col] + smS[1][col]; q = smQ[0][col] + smQ[1][col]; }
        else          { s = smS[2][col] + smS[3][col]; q = smQ[2][col] + smQ[3][col]; }
        atomicAdd(&stats_out[col], s);
        atomicAdd(&stats_out[HH + col], q);
    }
}

// --- h_pooled = sum_n gp * relu(BN3(t3 bf16)); 512 blocks ---
__global__ __launch_bounds__(256) void k_hpool(const unsigned short* __restrict__ t3,
                                               const float* __restrict__ gp,
                                               const float* __restrict__ stats3,
                                               float* __restrict__ hpool) {
    __shared__ float sm_mean[HH], sm_inv[HH];
    __shared__ float red[8][HH];
    int tid = threadIdx.x;
    if (tid < HH) {
        float s = stats3[tid], q = stats3[HH + tid];
        float m = s * (1.f / NROWS);
        sm_mean[tid] = m;
        sm_inv[tid] = 1.f / sqrtf(q * (1.f / NROWS) - m * m + 1e-5f);
    }
    __syncthreads();
    int b = blockIdx.x >> 3, chunk = blockIdx.x & 7;
    int c4 = tid & 31, rl = tid >> 5;
    float4 mm = *(const float4*)&sm_mean[c4 * 4];
    float4 iv = *(const float4*)&sm_inv[c4 * 4];
    float a0 = 0.f, a1 = 0.f, a2 = 0.f, a3 = 0.f;
    int nend = chunk * 75 + 75;
    for (int n = chunk * 75 + rl; n < nend; n += 8) {
        float w = gp[b * NN + n];
        uint2 t = *(const uint2*)&t3[((size_t)b * NN + n) * HH + c4 * 4];
        a0 += w * fmaxf((bf2f(t.x & 0xffffu) - mm.x) * iv.x, 0.f);
        a1 += w * fmaxf((bf2f(t.x >> 16)     - mm.y) * iv.y, 0.f);
        a2 += w * fmaxf((bf2f(t.y & 0xffffu) - mm.z) * iv.z, 0.f);
        a3 += w * fmaxf((bf2f(t.y >> 16)     - mm.w) * iv.w, 0.f);
    }
    *(float4*)&red[rl][c4 * 4] = make_float4(a0, a1, a2, a3);
    __syncthreads();
    if (tid < HH) {
        float s = 0.f;
#pragma unroll
        for (int g = 0; g < 8; ++g) s += red[g][tid];
        atomicAdd(&hpool[b * HH + tid], s);
    }
}

// --- fused actor head: concat rows in LDS -> a1 -> a2 -> scores. 8 rows/block. ---
__global__ __launch_bounds__(256) void k_actor(const unsigned short* __restrict__ t3,
                                               const int* __restrict__ cand,
                                               const float* __restrict__ hpool,
                                               const float* __restrict__ mch,
                                               const float* __restrict__ stats3,
                                               const float* __restrict__ Wa1,
                                               const float* __restrict__ ba1,
                                               const float* __restrict__ Wa2,
                                               const float* __restrict__ ba2,
                                               const float* __restrict__ Wa3,
                                               const float* __restrict__ ba3,
                                               float* __restrict__ scores) {
    __shared__ float sh_c[8 * 384];
    __shared__ float sh_a1[8 * HH];
    __shared__ float sred[8][HH];
    int tid = threadIdx.x;
    int rbase = blockIdx.x * 8;
    int c = tid & 127, slot = tid >> 7;

    float mean_c, inv_c;
    {
        float s = stats3[c], q = stats3[HH + c];
        float m = s * (1.f / NROWS);
        mean_c = m;
        inv_c = 1.f / sqrtf(q * (1.f / NROWS) - m * m + 1e-5f);
    }
#pragma unroll
    for (int rr = 0; rr < 4; ++rr) {
        int r = slot * 4 + rr;
        int row = rbase + r;
        int b = row / NJ;
        int cd = cand[row];
        float v = bf2f(t3[((size_t)b * NN + cd) * HH + c]);
        sh_c[r * 384 + c]       = fmaxf((v - mean_c) * inv_c, 0.f);
        sh_c[r * 384 + 128 + c] = hpool[b * HH + c];
        sh_c[r * 384 + 256 + c] = mch[b * HH + c];
    }
    __syncthreads();

    float acc[4] = {0.f, 0.f, 0.f, 0.f};
    for (int k = 0; k < 384; ++k) {
        float w = Wa1[(size_t)k * HH + c];
#pragma unroll
        for (int rr = 0; rr < 4; ++rr)
            acc[rr] += sh_c[(slot * 4 + rr) * 384 + k] * w;
    }
    float bb = ba1[c];
#pragma unroll
    for (int rr = 0; rr < 4; ++rr)
        sh_a1[(slot * 4 + rr) * HH + c] = tanhf(acc[rr] + bb);
    __syncthreads();

    float acc2[4] = {0.f, 0.f, 0.f, 0.f};
    for (int k = 0; k < HH; ++k) {
        float w = Wa2[(size_t)k * HH + c];
#pragma unroll
        for (int rr = 0; rr < 4; ++rr)
            acc2[rr] += sh_a1[(slot * 4 + rr) * HH + k] * w;
    }
    float w3 = Wa3[c], bb2 = ba2[c];
#pragma unroll
    for (int rr = 0; rr < 4; ++rr)
        sred[slot * 4 + rr][c] = tanhf(acc2[rr] + bb2) * w3;
    __syncthreads();
    int r = tid >> 5, l32 = tid & 31;
    float v = sred[r][l32] + sred[r][l32 + 32] + sred[r][l32 + 64] + sred[r][l32 + 96];
    v += __shfl_xor(v, 1); v += __shfl_xor(v, 2); v += __shfl_xor(v, 4);
    v += __shfl_xor(v, 8); v += __shfl_xor(v, 16);
    if (l32 == 0) scores[rbase + r] = 10.f * (v + ba3[0]);
}

// --- per-b: critic, masked log_softmax/entropy/log_a, gathers ---
__global__ __launch_bounds__(128) void k_final(const unsigned short* __restrict__ t3,
                                               const float* __restrict__ stats3,
                                               const float* __restrict__ hpool,
                                               const float* __restrict__ scores,
                                               const void* __restrict__ mask_p,
                                               const void* __restrict__ maskmch_p,
                                               const int* __restrict__ flags,
                                               const float* __restrict__ dur,
                                               const int* __restrict__ a_index,
                                               const int* __restrict__ old_action,
                                               const float* __restrict__ Wc1,
                                               const float* __restrict__ bc1,
                                               const float* __restrict__ Wc2,
                                               const float* __restrict__ bc2,
                                               float* __restrict__ out) {
    __shared__ float sm_mean[HH], sm_inv[HH], sh_hp[HH], sh_red[HH];
    __shared__ float sh_s[32], sh_lp[32];
    __shared__ int sh_m[32];
    int b = blockIdx.x, t = threadIdx.x;
    {
        float s = stats3[t], q = stats3[HH + t];
        float m = s * (1.f / NROWS);
        sm_mean[t] = m;
        sm_inv[t] = 1.f / sqrtf(q * (1.f / NROWS) - m * m + 1e-5f);
    }
    sh_hp[t] = hpool[b * HH + t];
    __syncthreads();

    float acc = bc1[t];
    for (int k = 0; k < HH; ++k) acc += sh_hp[k] * Wc1[k * HH + t];
    sh_red[t] = tanhf(acc) * Wc2[t];
    __syncthreads();
    for (int st = 64; st > 0; st >>= 1) {
        if (t < st) sh_red[t] += sh_red[t + st];
        __syncthreads();
    }
    if (t == 0) out[OUT_V + b] = sh_red[0] + bc2[0];

    int fA = flags[0], fB = flags[1];
    int layA = (fA & 1) ? 2 : ((fA & 2) ? 1 : 0);
    int layB = (fB & 1) ? 2 : ((fB & 2) ? 1 : 0);
    if (t < NJ) {
        sh_s[t] = scores[b * NJ + t];
        sh_m[t] = mask_at(mask_p, layA, (long)b * NJ + t) ? 1 : 0;
    }
    __syncthreads();
    if (t == 0) {
        float mx = -1e30f;
        for (int j = 0; j < NJ; ++j)
            if (!sh_m[j] && sh_s[j] > mx) mx = sh_s[j];
        float sum = 0.f;
        for (int j = 0; j < NJ; ++j)
            if (!sh_m[j]) sum += expf(sh_s[j] - mx);
        float lse = mx + logf(sum);
        float ent = 0.f;
        for (int j = 0; j < NJ; ++j) {
            if (!sh_m[j]) {
                float lp = sh_s[j] - lse;
                sh_lp[j] = lp;
                float pi = expf(lp);
                if (pi > 0.f) ent -= pi * lp;
            }
        }
        out[OUT_ENT + b] = ent;
        out[OUT_LOGA + b] = sh_lp[a_index[b]];
    }

    int old = old_action[b];
    if (t < NM) {
        out[OUT_ANODE + b * NM + t] = dur[((size_t)b * NN + old) * NM + t];
        out[OUT_MMCH + b * NM + t] =
            mask_at(maskmch_p, layB, ((size_t)b * NN + old) * NM + t) ? 1.f : 0.f;
    }
    {
        float v = bf2f(t3[((size_t)b * NN + old) * HH + t]);
        out[OUT_AFEAT + b * HH + t] = fmaxf((v - sm_mean[t]) * sm_inv[t], 0.f);
        out[OUT_HPOOL + b * HH + t] = sh_hp[t];
    }
}

extern "C" void kernel_launch(void* const* d_in, const int* in_sizes, int n_in,
                              void* d_out, int out_size, void* d_ws, size_t ws_size,
                              hipStream_t stream) {
    (void)in_sizes; (void)n_in; (void)out_size; (void)ws_size;
    const float* x         = (const float*)d_in[0];
    const float* gp        = (const float*)d_in[1];
    const float* adj       = (const float*)d_in[3];
    const int*   cand      = (const int*)d_in[4];
    const void*  mask_p    = d_in[5];
    const void*  maskmch_p = d_in[6];
    const float* dur       = (const float*)d_in[7];
    const int*   a_index   = (const int*)d_in[8];
    const int*   old_act   = (const int*)d_in[9];
    const float* mch_pool  = (const float*)d_in[10];
    const float* W1_0 = (const float*)d_in[11];
    const float* W2_0 = (const float*)d_in[13];
    const float* W1_1 = (const float*)d_in[15];
    const float* W2_1 = (const float*)d_in[17];
    const float* Wa1  = (const float*)d_in[19];
    const float* ba1  = (const float*)d_in[20];
    const float* Wa2  = (const float*)d_in[21];
    const float* ba2  = (const float*)d_in[22];
    const float* Wa3  = (const float*)d_in[23];
    const float* ba3  = (const float*)d_in[24];
    const float* Wc1  = (const float*)d_in[25];
    const float* bc1  = (const float*)d_in[26];
    const float* Wc2  = (const float*)d_in[27];
    const float* bc2  = (const float*)d_in[28];

    char* ws = (char*)d_ws;
    float* stats   = (float*)(ws + STATS_B);
    float* hpool   = (float*)(ws + HPOOL_B);
    int*   flags   = (int*)(ws + FLAGS_B);
    unsigned short* wtb = (unsigned short*)(ws + WTB_B);
    float* scores  = (float*)(ws + SCORES_B);
    int*   nbr_cnt = (int*)(ws + NBRCNT_B);
    int*   nbr_idx = (int*)(ws + NBRIDX_B);
    float* pooled0 = (float*)(ws + POOLED0_B);
    unsigned short* t1_16 = (unsigned short*)(ws + T1_B);  // t1, then t3 (bf16)
    unsigned short* t2_16 = (unsigned short*)(ws + P1_B);  // t2 (bf16)
    float* out     = (float*)d_out;

    hipMemsetAsync(ws, 0, ZERO_B, stream);
    k_sparse<<<NROWS / 4, 256, 0, stream>>>(adj, x, nbr_cnt, nbr_idx, pooled0,
                                            mask_p, maskmch_p, flags, W2_0, W1_1, W2_1, wtb);
    k_p0stats<<<NROWS / 256, 256, 0, stream>>>(pooled0, stats);
    // t1(bf16) = relu(BN0(pooled0 @ W1_0)) @ W2_0   [+ stats1]
    k_stage<0><<<2400, 256, 0, stream>>>(nullptr, pooled0, W1_0, wtb, stats, t1_16, stats + 256);
    // t2(bf16) = (sum_nbr relu(BN1(t1))) @ W1_1   [+ stats2]  (ping-pong, no in-place)
    k_poolstage<<<NROWS / 32, 256, 0, stream>>>(t1_16, nbr_cnt, nbr_idx, stats + 256,
                                                wtb + 16384, t2_16, stats + 512);
    // t3(bf16) = relu(BN2(t2)) @ W2_1   [+ stats3]  — in t2_16, out t1_16
    k_stage<1><<<2400, 256, 0, stream>>>(t2_16, nullptr, nullptr, wtb + 32768, stats + 512,
                                         t1_16, stats + 768);
    k_hpool<<<BB * 8, 256, 0, stream>>>(t1_16, gp, stats + 768, hpool);
    k_actor<<<240, 256, 0, stream>>>(t1_16, cand, hpool, mch_pool, stats + 768,
                                     Wa1, ba1, Wa2, ba2, Wa3, ba3, scores);
    k_final<<<BB, 128, 0, stream>>>(t1_16, stats + 768, hpool, scores, mask_p, maskmch_p, flags,
                                    dur, a_index, old_act, Wc1, bc1, Wc2, bc2, out);
}

// Round 11
// 350.365 us; speedup vs baseline: 1.1295x; 1.0274x over previous
//
#include <hip/hip_runtime.h>
#include <hip/hip_bf16.h>

#define BB 64
#define NJ 30
#define NM 20
#define NN 600
#define HH 128
#define NROWS (BB*NN)   // 38400
#define CAP 48          // max neighbors kept (E~7, P(>47) ~ 0)

typedef __attribute__((ext_vector_type(8))) short short8;
typedef __attribute__((ext_vector_type(4))) float f32x4;

// ---- workspace byte offsets ----
#define STATS_B   0           // slot0: 5 scalars; slots1-3: sum[128],sq[128]
#define HPOOL_B   4096
#define FLAGS_B   36864
#define ZERO_B    36880       // memset range
#define WTB_B     37120       // 3 x 128x128 bf16 transposed weights (98304 B)
#define SCORES_B  135424
#define NBRCNT_B  143104
#define NBRIDX_B  296704      // NROWS*CAP ints (7372800 B)
#define POOLED0_B 7669504     // NROWS * 2 floats
#define T1_B      7976704     // NROWS*H bf16: t1, then t2 (9.83 MB)
#define P1_B      27637504    // NROWS*H bf16: pooled1, then t3 (9.83 MB)

// ---- output float offsets ----
#define OUT_ENT   0
#define OUT_V     64
#define OUT_LOGA  128
#define OUT_ANODE 192
#define OUT_AFEAT 1472
#define OUT_MMCH  9664
#define OUT_HPOOL 10944

__device__ __forceinline__ bool mask_at(const void* p, int layout, long i) {
    if (layout == 2) return ((const float*)p)[i] != 0.f;
    if (layout == 1) return ((const unsigned char*)p)[i] != 0;
    return ((const int*)p)[i] != 0;
}

__device__ __forceinline__ short bf16rne(float f) {
    unsigned u = __float_as_uint(f);
    return (short)((u + 0x7fffu + ((u >> 16) & 1u)) >> 16);
}
__device__ __forceinline__ float bf2f(unsigned h) {
    return __uint_as_float(h << 16);
}
__device__ __forceinline__ unsigned packbf(float a, float b) {
    return ((unsigned)(unsigned short)bf16rne(a)) |
           (((unsigned)(unsigned short)bf16rne(b)) << 16);
}

// --- scan adj once: neighbor lists + pooled0 = sum_nbr x (shfl_up scan).
//     First 289 blocks additionally do the prologue (mask-layout detect
//     blocks 0..96, weight transpose/cvt blocks 97..288). ---
__global__ __launch_bounds__(256) void k_sparse(const float* __restrict__ adj,
                                                const float* __restrict__ x,
                                                int* __restrict__ nbr_cnt,
                                                int* __restrict__ nbr_idx,
                                                float* __restrict__ pooled0,
                                                const void* mask_p, const void* maskmch_p,
                                                int* flags,
                                                const float* __restrict__ Wa,
                                                const float* __restrict__ Wb,
                                                const float* __restrict__ Wc,
                                                unsigned short* __restrict__ wT) {
    int bid = blockIdx.x;
    int tid = threadIdx.x;
    if (bid < 289) {
        if (bid >= 97) {   // wconv: wT[c][k] = bf16(W[k][c])
            int bid2 = bid - 97;
            int mat = bid2 >> 6;
            int idx = ((bid2 & 63) << 8) + tid;
            const float* W = mat == 0 ? Wa : (mat == 1 ? Wb : Wc);
            int k = idx >> 7, c = idx & 127;
            wT[mat * 16384 + c * HH + k] = (unsigned short)bf16rne(W[idx]);
        } else {
            unsigned agg = 0;
            int which;
            if (bid == 0) {
                which = 0;
                const unsigned* p = (const unsigned*)mask_p;     // 480 words
                unsigned w0 = (tid < 480) ? p[tid] : 0u;
                unsigned w1 = (tid + 256 < 480) ? p[tid + 256] : 0u;
                agg = w0 | w1;
            } else {
                which = 1;
                const unsigned* p = (const unsigned*)maskmch_p + (size_t)(bid - 1) * 200;
                agg = (tid < 200) ? p[tid] : 0u;                 // 96 blocks x 200 words
            }
            int f = 0;
            if (((agg >> 24) & 0xffu) == 0x3fu) f |= 1;
            if ((((agg >> 8) & 0xffu) == 1u) || (((agg >> 16) & 0xffu) == 1u) ||
                (((agg >> 24) & 0xffu) == 1u)) f |= 2;
#pragma unroll
            for (int off = 1; off < 64; off <<= 1) f |= __shfl_xor(f, off);
            if ((tid & 63) == 0 && f) atomicOr(&flags[which], f);
        }
    }

    int wrow = bid * 4 + (tid >> 6);
    int lane = tid & 63;
    int b = wrow / NN;
    const float4* arow = (const float4*)(adj + (size_t)wrow * NN);
    int* irow = nbr_idx + (size_t)wrow * CAP;
    const float* xb = x + (size_t)b * NN * 2;
    float4 vv[3];
    vv[0] = arow[lane];
    vv[1] = arow[64 + lane];
    vv[2] = (128 + lane < 150) ? arow[128 + lane] : make_float4(0.f, 0.f, 0.f, 0.f);
    int cnt = 0;
    float p0 = 0.f, p1 = 0.f;
#pragma unroll
    for (int it = 0; it < 3; ++it) {
        float4 v = vv[it];
        int col0 = it * 256 + lane * 4;
        bool m0 = v.x != 0.f, m1 = v.y != 0.f, m2 = v.z != 0.f, m3 = v.w != 0.f;
        int c_lane = (int)m0 + (int)m1 + (int)m2 + (int)m3;
        int inc = c_lane;
#pragma unroll
        for (int off = 1; off < 64; off <<= 1) {
            int t = __shfl_up(inc, off);
            if (lane >= off) inc += t;
        }
        int pos = cnt + inc - c_lane;
        if (m0) {
            if (pos < CAP) irow[pos] = col0;
            float2 xv = *(const float2*)&xb[col0 * 2];
            p0 += xv.x; p1 += xv.y; ++pos;
        }
        if (m1) {
            if (pos < CAP) irow[pos] = col0 + 1;
            float2 xv = *(const float2*)&xb[(col0 + 1) * 2];
            p0 += xv.x; p1 += xv.y; ++pos;
        }
        if (m2) {
            if (pos < CAP) irow[pos] = col0 + 2;
            float2 xv = *(const float2*)&xb[(col0 + 2) * 2];
            p0 += xv.x; p1 += xv.y; ++pos;
        }
        if (m3) {
            if (pos < CAP) irow[pos] = col0 + 3;
            float2 xv = *(const float2*)&xb[(col0 + 3) * 2];
            p0 += xv.x; p1 += xv.y; ++pos;
        }
        cnt += __shfl(inc, 63);
    }
#pragma unroll
    for (int off = 1; off < 64; off <<= 1) {
        p0 += __shfl_xor(p0, off);
        p1 += __shfl_xor(p1, off);
    }
    if (lane == 0) {
        nbr_cnt[wrow] = cnt < CAP ? cnt : CAP;
        pooled0[(size_t)wrow * 2]     = p0;
        pooled0[(size_t)wrow * 2 + 1] = p1;
    }
}

// --- 5-scalar stats over pooled0 ---
__global__ __launch_bounds__(256) void k_p0stats(const float* __restrict__ pooled0,
                                                 float* __restrict__ out5) {
    __shared__ float red[4][5];
    int i = blockIdx.x * 256 + threadIdx.x;
    float p0 = pooled0[(size_t)i * 2], p1 = pooled0[(size_t)i * 2 + 1];
    float v[5] = {p0, p1, p0 * p0, p1 * p1, p0 * p1};
#pragma unroll
    for (int j = 0; j < 5; ++j)
#pragma unroll
        for (int off = 1; off < 64; off <<= 1) v[j] += __shfl_xor(v[j], off);
    int lane = threadIdx.x & 63, w = threadIdx.x >> 6;
    if (lane == 0)
#pragma unroll
        for (int j = 0; j < 5; ++j) red[w][j] = v[j];
    __syncthreads();
    if (threadIdx.x == 0)
#pragma unroll
        for (int j = 0; j < 5; ++j)
            atomicAdd(&out5[j], red[0][j] + red[1][j] + red[2][j] + red[3][j]);
}

// --- MFMA GEMM stage, column-split: 2400 blocks;
//     block bx: rows (bx>>2)*64..+63, cols (bx&3)*32..+31.
//     MODE 0: A synthesized from pooled0; MODE 1: A=relu(BN(t_in));
//     MODE 2: A = t_in raw bf16 (already normalized+relu'd). ---
template<int MODE>
__global__ __launch_bounds__(256) void k_stage(const void* __restrict__ t_in_v,
                                               const float* __restrict__ pooled0,
                                               const float* __restrict__ W1,
                                               const unsigned short* __restrict__ wT,
                                               const float* __restrict__ stats_in,
                                               unsigned short* __restrict__ t_out,
                                               float* __restrict__ stats_out) {
    __shared__ float sm_mean[HH], sm_inv[HH];
    __shared__ float smS[4][32], smQ[4][32];
    int tid = threadIdx.x;
    if (MODE == 0 && tid < HH) {
        float S0 = stats_in[0], S1 = stats_in[1], Q0 = stats_in[2], Q1 = stats_in[3], P01 = stats_in[4];
        float w0 = W1[tid], w1 = W1[HH + tid];
        float m = (S0 * w0 + S1 * w1) * (1.f / NROWS);
        float eq = (Q0 * w0 * w0 + Q1 * w1 * w1 + 2.f * P01 * w0 * w1) * (1.f / NROWS);
        sm_mean[tid] = m;
        sm_inv[tid] = 1.f / sqrtf(eq - m * m + 1e-5f);
    }
    if (MODE == 1 && tid < HH) {
        float s = stats_in[tid], q = stats_in[HH + tid];
        float m = s * (1.f / NROWS);
        sm_mean[tid] = m;
        sm_inv[tid] = 1.f / sqrtf(q * (1.f / NROWS) - m * m + 1e-5f);
    }
    if (MODE != 2) __syncthreads();

    const unsigned short* tin = (const unsigned short*)t_in_v;
    int lane = tid & 63, wave = tid >> 6;
    int r16 = lane & 15, kg = lane >> 4;
    int rowbase = (blockIdx.x >> 2) * 64 + wave * 16;
    int colq = blockIdx.x & 3;

    f32x4 acc[2];
#pragma unroll
    for (int t = 0; t < 2; ++t)
#pragma unroll
        for (int i = 0; i < 4; ++i) acc[t][i] = 0.f;

    float p0 = 0.f, p1 = 0.f;
    if (MODE == 0) {
        p0 = pooled0[(size_t)(rowbase + r16) * 2];
        p1 = pooled0[(size_t)(rowbase + r16) * 2 + 1];
    }

#pragma unroll
    for (int ks = 0; ks < 4; ++ks) {
        int kb = ks * 32 + kg * 8;
        short8 afr;
        if (MODE == 2) {
            afr = *(const short8*)&tin[(size_t)(rowbase + r16) * HH + kb];
        } else {
            float av[8];
            if (MODE == 0) {
                float4 wa0 = *(const float4*)&W1[kb];
                float4 wa1 = *(const float4*)&W1[kb + 4];
                float4 wb0 = *(const float4*)&W1[HH + kb];
                float4 wb1 = *(const float4*)&W1[HH + kb + 4];
                av[0] = p0 * wa0.x + p1 * wb0.x; av[1] = p0 * wa0.y + p1 * wb0.y;
                av[2] = p0 * wa0.z + p1 * wb0.z; av[3] = p0 * wa0.w + p1 * wb0.w;
                av[4] = p0 * wa1.x + p1 * wb1.x; av[5] = p0 * wa1.y + p1 * wb1.y;
                av[6] = p0 * wa1.z + p1 * wb1.z; av[7] = p0 * wa1.w + p1 * wb1.w;
            } else {
                short8 raw = *(const short8*)&tin[(size_t)(rowbase + r16) * HH + kb];
#pragma unroll
                for (int j = 0; j < 8; ++j) av[j] = bf2f((unsigned short)raw[j]);
            }
            float4 m0 = *(const float4*)&sm_mean[kb];
            float4 m1 = *(const float4*)&sm_mean[kb + 4];
            float4 i0 = *(const float4*)&sm_inv[kb];
            float4 i1 = *(const float4*)&sm_inv[kb + 4];
            av[0] = fmaxf((av[0] - m0.x) * i0.x, 0.f);
            av[1] = fmaxf((av[1] - m0.y) * i0.y, 0.f);
            av[2] = fmaxf((av[2] - m0.z) * i0.z, 0.f);
            av[3] = fmaxf((av[3] - m0.w) * i0.w, 0.f);
            av[4] = fmaxf((av[4] - m1.x) * i1.x, 0.f);
            av[5] = fmaxf((av[5] - m1.y) * i1.y, 0.f);
            av[6] = fmaxf((av[6] - m1.z) * i1.z, 0.f);
            av[7] = fmaxf((av[7] - m1.w) * i1.w, 0.f);
#pragma unroll
            for (int j = 0; j < 8; ++j) afr[j] = bf16rne(av[j]);
        }
#pragma unroll
        for (int t = 0; t < 2; ++t) {
            short8 bfr = *(const short8*)&wT[(size_t)((colq * 2 + t) * 16 + r16) * HH + kb];
            acc[t] = __builtin_amdgcn_mfma_f32_16x16x32_bf16(afr, bfr, acc[t], 0, 0, 0);
        }
    }

#pragma unroll
    for (int t = 0; t < 2; ++t) {
        int lc = t * 16 + r16;
        int col = colq * 32 + lc;
        float s = 0.f, q = 0.f;
#pragma unroll
        for (int i = 0; i < 4; ++i) {
            float v = acc[t][i];
            t_out[(size_t)(rowbase + kg * 4 + i) * HH + col] = (unsigned short)bf16rne(v);
            s += v; q += v * v;
        }
        s += __shfl_xor(s, 16); q += __shfl_xor(q, 16);
        s += __shfl_xor(s, 32); q += __shfl_xor(q, 32);
        if (kg == 0) { smS[wave][lc] = s; smQ[wave][lc] = q; }
    }
    __syncthreads();
    if (tid < 32) {
        int col = colq * 32 + tid;
        atomicAdd(&stats_out[col],      smS[0][tid] + smS[1][tid] + smS[2][tid] + smS[3][tid]);
        atomicAdd(&stats_out[HH + col], smQ[0][tid] + smQ[1][tid] + smQ[2][tid] + smQ[3][tid]);
    }
}

// --- pooled1(bf16) = sum_nbr relu(BN1(t1 bf16)); 4800 blocks, 2-way unroll ---
__global__ __launch_bounds__(256) void k_pool1(const unsigned short* __restrict__ t1,
                                               const int* __restrict__ nbr_cnt,
                                               const int* __restrict__ nbr_idx,
                                               const float* __restrict__ stats1,
                                               unsigned short* __restrict__ pooled1) {
    __shared__ float sm_mean[HH], sm_inv[HH];
    int tid = threadIdx.x;
    if (tid < HH) {
        float s = stats1[tid], q = stats1[HH + tid];
        float m = s * (1.f / NROWS);
        sm_mean[tid] = m;
        sm_inv[tid] = 1.f / sqrtf(q * (1.f / NROWS) - m * m + 1e-5f);
    }
    __syncthreads();
    int c4 = tid & 31, rl = tid >> 5;
    int row = blockIdx.x * 8 + rl;
    int b = row / NN;
    float4 mm = *(const float4*)&sm_mean[c4 * 4];
    float4 iv = *(const float4*)&sm_inv[c4 * 4];
    int cnt = nbr_cnt[row];
    const int* ir = nbr_idx + (size_t)row * CAP;
    const unsigned short* tb = t1 + (size_t)b * NN * HH;
    float a0 = 0.f, a1 = 0.f, a2 = 0.f, a3 = 0.f;
    int i = 0;
    for (; i + 1 < cnt; i += 2) {
        int m0 = ir[i], m1 = ir[i + 1];
        uint2 w0 = *(const uint2*)&tb[(size_t)m0 * HH + c4 * 4];
        uint2 w1 = *(const uint2*)&tb[(size_t)m1 * HH + c4 * 4];
        a0 += fmaxf((bf2f(w0.x & 0xffffu) - mm.x) * iv.x, 0.f)
            + fmaxf((bf2f(w1.x & 0xffffu) - mm.x) * iv.x, 0.f);
        a1 += fmaxf((bf2f(w0.x >> 16)     - mm.y) * iv.y, 0.f)
            + fmaxf((bf2f(w1.x >> 16)     - mm.y) * iv.y, 0.f);
        a2 += fmaxf((bf2f(w0.y & 0xffffu) - mm.z) * iv.z, 0.f)
            + fmaxf((bf2f(w1.y & 0xffffu) - mm.z) * iv.z, 0.f);
        a3 += fmaxf((bf2f(w0.y >> 16)     - mm.w) * iv.w, 0.f)
            + fmaxf((bf2f(w1.y >> 16)     - mm.w) * iv.w, 0.f);
    }
    if (i < cnt) {
        int m0 = ir[i];
        uint2 w0 = *(const uint2*)&tb[(size_t)m0 * HH + c4 * 4];
        a0 += fmaxf((bf2f(w0.x & 0xffffu) - mm.x) * iv.x, 0.f);
        a1 += fmaxf((bf2f(w0.x >> 16)     - mm.y) * iv.y, 0.f);
        a2 += fmaxf((bf2f(w0.y & 0xffffu) - mm.z) * iv.z, 0.f);
        a3 += fmaxf((bf2f(w0.y >> 16)     - mm.w) * iv.w, 0.f);
    }
    uint2 o;
    o.x = packbf(a0, a1);
    o.y = packbf(a2, a3);
    *(uint2*)&pooled1[(size_t)row * HH + c4 * 4] = o;
}

// --- h_pooled = sum_n gp * relu(BN3(t3 bf16)); 512 blocks ---
__global__ __launch_bounds__(256) void k_hpool(const unsigned short* __restrict__ t3,
                                               const float* __restrict__ gp,
                                               const float* __restrict__ stats3,
                                               float* __restrict__ hpool) {
    __shared__ float sm_mean[HH], sm_inv[HH];
    __shared__ float red[8][HH];
    int tid = threadIdx.x;
    if (tid < HH) {
        float s = stats3[tid], q = stats3[HH + tid];
        float m = s * (1.f / NROWS);
        sm_mean[tid] = m;
        sm_inv[tid] = 1.f / sqrtf(q * (1.f / NROWS) - m * m + 1e-5f);
    }
    __syncthreads();
    int b = blockIdx.x >> 3, chunk = blockIdx.x & 7;
    int c4 = tid & 31, rl = tid >> 5;
    float4 mm = *(const float4*)&sm_mean[c4 * 4];
    float4 iv = *(const float4*)&sm_inv[c4 * 4];
    float a0 = 0.f, a1 = 0.f, a2 = 0.f, a3 = 0.f;
    int nend = chunk * 75 + 75;
    for (int n = chunk * 75 + rl; n < nend; n += 8) {
        float w = gp[b * NN + n];
        uint2 t = *(const uint2*)&t3[((size_t)b * NN + n) * HH + c4 * 4];
        a0 += w * fmaxf((bf2f(t.x & 0xffffu) - mm.x) * iv.x, 0.f);
        a1 += w * fmaxf((bf2f(t.x >> 16)     - mm.y) * iv.y, 0.f);
        a2 += w * fmaxf((bf2f(t.y & 0xffffu) - mm.z) * iv.z, 0.f);
        a3 += w * fmaxf((bf2f(t.y >> 16)     - mm.w) * iv.w, 0.f);
    }
    *(float4*)&red[rl][c4 * 4] = make_float4(a0, a1, a2, a3);
    __syncthreads();
    if (tid < HH) {
        float s = 0.f;
#pragma unroll
        for (int g = 0; g < 8; ++g) s += red[g][tid];
        atomicAdd(&hpool[b * HH + tid], s);
    }
}

// --- fused actor head: concat rows in LDS -> a1 -> a2 -> scores. 8 rows/block. ---
__global__ __launch_bounds__(256) void k_actor(const unsigned short* __restrict__ t3,
                                               const int* __restrict__ cand,
                                               const float* __restrict__ hpool,
                                               const float* __restrict__ mch,
                                               const float* __restrict__ stats3,
                                               const float* __restrict__ Wa1,
                                               const float* __restrict__ ba1,
                                               const float* __restrict__ Wa2,
                                               const float* __restrict__ ba2,
                                               const float* __restrict__ Wa3,
                                               const float* __restrict__ ba3,
                                               float* __restrict__ scores) {
    __shared__ float sh_c[8 * 384];
    __shared__ float sh_a1[8 * HH];
    __shared__ float sred[8][HH];
    int tid = threadIdx.x;
    int rbase = blockIdx.x * 8;
    int c = tid & 127, slot = tid >> 7;

    float mean_c, inv_c;
    {
        float s = stats3[c], q = stats3[HH + c];
        float m = s * (1.f / NROWS);
        mean_c = m;
        inv_c = 1.f / sqrtf(q * (1.f / NROWS) - m * m + 1e-5f);
    }
#pragma unroll
    for (int rr = 0; rr < 4; ++rr) {
        int r = slot * 4 + rr;
        int row = rbase + r;
        int b = row / NJ;
        int cd = cand[row];
        float v = bf2f(t3[((size_t)b * NN + cd) * HH + c]);
        sh_c[r * 384 + c]       = fmaxf((v - mean_c) * inv_c, 0.f);
        sh_c[r * 384 + 128 + c] = hpool[b * HH + c];
        sh_c[r * 384 + 256 + c] = mch[b * HH + c];
    }
    __syncthreads();

    float acc[4] = {0.f, 0.f, 0.f, 0.f};
    for (int k = 0; k < 384; ++k) {
        float w = Wa1[(size_t)k * HH + c];
#pragma unroll
        for (int rr = 0; rr < 4; ++rr)
            acc[rr] += sh_c[(slot * 4 + rr) * 384 + k] * w;
    }
    float bb = ba1[c];
#pragma unroll
    for (int rr = 0; rr < 4; ++rr)
        sh_a1[(slot * 4 + rr) * HH + c] = tanhf(acc[rr] + bb);
    __syncthreads();

    float acc2[4] = {0.f, 0.f, 0.f, 0.f};
    for (int k = 0; k < HH; ++k) {
        float w = Wa2[(size_t)k * HH + c];
#pragma unroll
        for (int rr = 0; rr < 4; ++rr)
            acc2[rr] += sh_a1[(slot * 4 + rr) * HH + k] * w;
    }
    float w3 = Wa3[c], bb2 = ba2[c];
#pragma unroll
    for (int rr = 0; rr < 4; ++rr)
        sred[slot * 4 + rr][c] = tanhf(acc2[rr] + bb2) * w3;
    __syncthreads();
    int r = tid >> 5, l32 = tid & 31;
    float v = sred[r][l32] + sred[r][l32 + 32] + sred[r][l32 + 64] + sred[r][l32 + 96];
    v += __shfl_xor(v, 1); v += __shfl_xor(v, 2); v += __shfl_xor(v, 4);
    v += __shfl_xor(v, 8); v += __shfl_xor(v, 16);
    if (l32 == 0) scores[rbase + r] = 10.f * (v + ba3[0]);
}

// --- per-b: critic, masked log_softmax/entropy/log_a, gathers ---
__global__ __launch_bounds__(128) void k_final(const unsigned short* __restrict__ t3,
                                               const float* __restrict__ stats3,
                                               const float* __restrict__ hpool,
                                               const float* __restrict__ scores,
                                               const void* __restrict__ mask_p,
                                               const void* __restrict__ maskmch_p,
                                               const int* __restrict__ flags,
                                               const float* __restrict__ dur,
                                               const int* __restrict__ a_index,
                                               const int* __restrict__ old_action,
                                               const float* __restrict__ Wc1,
                                               const float* __restrict__ bc1,
                                               const float* __restrict__ Wc2,
                                               const float* __restrict__ bc2,
                                               float* __restrict__ out) {
    __shared__ float sm_mean[HH], sm_inv[HH], sh_hp[HH], sh_red[HH];
    __shared__ float sh_s[32], sh_lp[32];
    __shared__ int sh_m[32];
    int b = blockIdx.x, t = threadIdx.x;
    {
        float s = stats3[t], q = stats3[HH + t];
        float m = s * (1.f / NROWS);
        sm_mean[t] = m;
        sm_inv[t] = 1.f / sqrtf(q * (1.f / NROWS) - m * m + 1e-5f);
    }
    sh_hp[t] = hpool[b * HH + t];
    __syncthreads();

    float acc = bc1[t];
    for (int k = 0; k < HH; ++k) acc += sh_hp[k] * Wc1[k * HH + t];
    sh_red[t] = tanhf(acc) * Wc2[t];
    __syncthreads();
    for (int st = 64; st > 0; st >>= 1) {
        if (t < st) sh_red[t] += sh_red[t + st];
        __syncthreads();
    }
    if (t == 0) out[OUT_V + b] = sh_red[0] + bc2[0];

    int fA = flags[0], fB = flags[1];
    int layA = (fA & 1) ? 2 : ((fA & 2) ? 1 : 0);
    int layB = (fB & 1) ? 2 : ((fB & 2) ? 1 : 0);
    if (t < NJ) {
        sh_s[t] = scores[b * NJ + t];
        sh_m[t] = mask_at(mask_p, layA, (long)b * NJ + t) ? 1 : 0;
    }
    __syncthreads();
    if (t == 0) {
        float mx = -1e30f;
        for (int j = 0; j < NJ; ++j)
            if (!sh_m[j] && sh_s[j] > mx) mx = sh_s[j];
        float sum = 0.f;
        for (int j = 0; j < NJ; ++j)
            if (!sh_m[j]) sum += expf(sh_s[j] - mx);
        float lse = mx + logf(sum);
        float ent = 0.f;
        for (int j = 0; j < NJ; ++j) {
            if (!sh_m[j]) {
                float lp = sh_s[j] - lse;
                sh_lp[j] = lp;
                float pi = expf(lp);
                if (pi > 0.f) ent -= pi * lp;
            }
        }
        out[OUT_ENT + b] = ent;
        out[OUT_LOGA + b] = sh_lp[a_index[b]];
    }

    int old = old_action[b];
    if (t < NM) {
        out[OUT_ANODE + b * NM + t] = dur[((size_t)b * NN + old) * NM + t];
        out[OUT_MMCH + b * NM + t] =
            mask_at(maskmch_p, layB, ((size_t)b * NN + old) * NM + t) ? 1.f : 0.f;
    }
    {
        float v = bf2f(t3[((size_t)b * NN + old) * HH + t]);
        out[OUT_AFEAT + b * HH + t] = fmaxf((v - sm_mean[t]) * sm_inv[t], 0.f);
        out[OUT_HPOOL + b * HH + t] = sh_hp[t];
    }
}

extern "C" void kernel_launch(void* const* d_in, const int* in_sizes, int n_in,
                              void* d_out, int out_size, void* d_ws, size_t ws_size,
                              hipStream_t stream) {
    (void)in_sizes; (void)n_in; (void)out_size; (void)ws_size;
    const float* x         = (const float*)d_in[0];
    const float* gp        = (const float*)d_in[1];
    const float* adj       = (const float*)d_in[3];
    const int*   cand      = (const int*)d_in[4];
    const void*  mask_p    = d_in[5];
    const void*  maskmch_p = d_in[6];
    const float* dur       = (const float*)d_in[7];
    const int*   a_index   = (const int*)d_in[8];
    const int*   old_act   = (const int*)d_in[9];
    const float* mch_pool  = (const float*)d_in[10];
    const float* W1_0 = (const float*)d_in[11];
    const float* W2_0 = (const float*)d_in[13];
    const float* W1_1 = (const float*)d_in[15];
    const float* W2_1 = (const float*)d_in[17];
    const float* Wa1  = (const float*)d_in[19];
    const float* ba1  = (const float*)d_in[20];
    const float* Wa2  = (const float*)d_in[21];
    const float* ba2  = (const float*)d_in[22];
    const float* Wa3  = (const float*)d_in[23];
    const float* ba3  = (const float*)d_in[24];
    const float* Wc1  = (const float*)d_in[25];
    const float* bc1  = (const float*)d_in[26];
    const float* Wc2  = (const float*)d_in[27];
    const float* bc2  = (const float*)d_in[28];

    char* ws = (char*)d_ws;
    float* stats   = (float*)(ws + STATS_B);
    float* hpool   = (float*)(ws + HPOOL_B);
    int*   flags   = (int*)(ws + FLAGS_B);
    unsigned short* wtb = (unsigned short*)(ws + WTB_B);
    float* scores  = (float*)(ws + SCORES_B);
    int*   nbr_cnt = (int*)(ws + NBRCNT_B);
    int*   nbr_idx = (int*)(ws + NBRIDX_B);
    float* pooled0 = (float*)(ws + POOLED0_B);
    unsigned short* t1_16 = (unsigned short*)(ws + T1_B);  // t1, then t2 (bf16)
    unsigned short* p1_16 = (unsigned short*)(ws + P1_B);  // pooled1, then t3 (bf16)
    float* out     = (float*)d_out;

    hipMemsetAsync(ws, 0, ZERO_B, stream);
    k_sparse<<<NROWS / 4, 256, 0, stream>>>(adj, x, nbr_cnt, nbr_idx, pooled0,
                                            mask_p, maskmch_p, flags, W2_0, W1_1, W2_1, wtb);
    k_p0stats<<<NROWS / 256, 256, 0, stream>>>(pooled0, stats);
    // t1(bf16) = relu(BN0(pooled0 @ W1_0)) @ W2_0   [+ stats1]
    k_stage<0><<<2400, 256, 0, stream>>>(nullptr, pooled0, W1_0, wtb, stats, t1_16, stats + 256);
    // pooled1(bf16) = sum_nbr relu(BN1(t1))
    k_pool1<<<NROWS / 8, 256, 0, stream>>>(t1_16, nbr_cnt, nbr_idx, stats + 256, p1_16);
    // t2(bf16) = pooled1 @ W1_1   [+ stats2]  (reads p1_16, writes t1_16 — t1 dead)
    k_stage<2><<<2400, 256, 0, stream>>>(p1_16, nullptr, nullptr, wtb + 16384, stats, t1_16, stats + 512);
    // t3(bf16) = relu(BN2(t2)) @ W2_1   [+ stats3]  (reads t1_16, writes p1_16)
    k_stage<1><<<2400, 256, 0, stream>>>(t1_16, nullptr, nullptr, wtb + 32768, stats + 512,
                                         p1_16, stats + 768);
    k_hpool<<<BB * 8, 256, 0, stream>>>(p1_16, gp, stats + 768, hpool);
    k_actor<<<240, 256, 0, stream>>>(p1_16, cand, hpool, mch_pool, stats + 768,
                                     Wa1, ba1, Wa2, ba2, Wa3, ba3, scores);
    k_final<<<BB, 128, 0, stream>>>(p1_16, stats + 768, hpool, scores, mask_p, maskmch_p, flags,
                                    dur, a_index, old_act, Wc1, bc1, Wc2, bc2, out);
}